// Round 19
// baseline (781.459 us; speedup 1.0000x reference)
//
#include <hip/hip_runtime.h>
#include <hip/hip_bf16.h>

#define N_NODES 65536
#define N_EDGES 1048576
#define IN_DIM 96
#define HID 128
#define OUTD 256
#define N_ACT 20

typedef unsigned short u16;
typedef unsigned char u8;
typedef unsigned int u32;
typedef __attribute__((ext_vector_type(8))) short bf16x8;
typedef __attribute__((ext_vector_type(4))) float f32x4;
typedef __attribute__((ext_vector_type(2))) float f32x2;

// intermediates bf16 (xr/hres) and fp8-e4m3 (xl, gather-path) ; all math fp32
__device__ __forceinline__ float bf2f(u16 v) { return __uint_as_float(((u32)v) << 16); }
__device__ __forceinline__ u16 f2bf(float f) {
    u32 x = __float_as_uint(f);
    return (u16)((x + 0x7fffu + ((x >> 16) & 1u)) >> 16);
}

// ---- fp8 via HW converters ----
__device__ __forceinline__ u8 ftofp8_hw(float f) {
    return (u8)((u32)__builtin_amdgcn_cvt_pk_fp8_f32(f, f, 0, false) & 0xffu);
}

// ---- DPP adds on the VALU pipe (ctrl must be a constant -> template) ----
template <int CTRL>
__device__ __forceinline__ float dppadd(float p) {
    return p + __uint_as_float((u32)__builtin_amdgcn_update_dpp(
        0, (int)__float_as_uint(p), CTRL, 0xF, 0xF, true));
}
// full-wave sum, result broadcast (readlane 63)
__device__ __forceinline__ float wave_sum_bcast(float p) {
    p = dppadd<0x111>(p);   // row_shr:1
    p = dppadd<0x112>(p);   // row_shr:2
    p = dppadd<0x114>(p);   // row_shr:4
    p = dppadd<0x118>(p);   // row_shr:8
    p = dppadd<0x142>(p);   // row_bcast15
    p = dppadd<0x143>(p);   // row_bcast31
    return __uint_as_float((u32)__builtin_amdgcn_readlane((int)__float_as_uint(p), 63));
}
// 16-lane (hw-row) sum, broadcast to all 16 lanes of the row.
__device__ __forceinline__ float red16(float p) {
    p = dppadd<0xB1>(p);
    p = dppadd<0x4E>(p);
    p = dppadd<0x141>(p);
    p = dppadd<0x140>(p);
    return p;
}

// ---------------- prep: zero deg/bcur + bf16 n-major weights + transpose Wq ----------------
__global__ __launch_bounds__(256) void k_prep(
    int* __restrict__ deg, int* __restrict__ bcur,
    const float* __restrict__ Wl, const float* __restrict__ Wr, const float* __restrict__ Wres,
    u16* __restrict__ wt,
    const float* __restrict__ W0, u16* __restrict__ wt0,
    const float* __restrict__ W1, u16* __restrict__ wt1,
    const float* __restrict__ Wq, float* __restrict__ wqT)
{
    int b = blockIdx.x, t = threadIdx.x;
    if (b < 256) {
        deg[b * 256 + t] = 0;
        if (b == 0 && t < 64) bcur[t] = 0;
    } else if (b < 640) {
        int idx = (b - 256) * 256 + t;        // 0..98303  gat weights [768][128]
        int nn = idx >> 7, k = idx & 127;
        float v;
        if (nn < 256) v = Wl[k * OUTD + nn];
        else if (nn < 512) v = Wr[k * OUTD + (nn - 256)];
        else v = Wres[k * OUTD + (nn - 512)];
        wt[idx] = f2bf(v);
    } else if (b < 688) {
        int idx = (b - 640) * 256 + t;        // 0..12287  W0^T [128][96]
        int nn = idx / 96, k = idx - nn * 96;
        wt0[idx] = f2bf(W0[k * HID + nn]);
    } else if (b < 752) {
        int idx = (b - 688) * 256 + t;        // 0..16383  W1^T [128][128]
        int nn = idx >> 7, k = idx & 127;
        wt1[idx] = f2bf(W1[k * HID + nn]);
    } else {
        int idx = (b - 752) * 256 + t;        // 0..5119   Wq^T [20][256]
        int q = idx >> 8, d = idx & 255;
        wqT[q * OUTD + d] = Wq[d * N_ACT + q];
    }
}

// ---------------- exclusive scan of degrees -> CSR offsets + 64-bucket degree histogram ----------------
__global__ __launch_bounds__(1024) void k_scan(const int* __restrict__ deg,
                                               int* __restrict__ off, int* __restrict__ boff) {
    __shared__ int part[1024];
    __shared__ int hist[64];
    int t = threadIdx.x;
    if (t < 64) hist[t] = 0;
    __syncthreads();
    int base = t * 64;
    const int4* d4 = (const int4*)(deg + base);
    int s = 0;
#pragma unroll
    for (int i = 0; i < 16; i++) {
        int4 v = d4[i];
        s += v.x + v.y + v.z + v.w;
        atomicAdd(&hist[v.x < 63 ? v.x : 63], 1);
        atomicAdd(&hist[v.y < 63 ? v.y : 63], 1);
        atomicAdd(&hist[v.z < 63 ? v.z : 63], 1);
        atomicAdd(&hist[v.w < 63 ? v.w : 63], 1);
    }
    part[t] = s;
    __syncthreads();
    if (t == 0) {
        int run = 0;
        for (int i = 0; i < 64; i++) { boff[i] = run; run += hist[i]; }
    }
    for (int o = 1; o < 1024; o <<= 1) {
        int v = (t >= o) ? part[t - o] : 0;
        __syncthreads();
        part[t] += v;
        __syncthreads();
    }
    int run = (t == 0) ? 0 : part[t - 1];
    int4* o4 = (int4*)(off + base);
#pragma unroll
    for (int i = 0; i < 16; i++) {
        int4 v = d4[i];
        int4 w;
        w.x = run;
        w.y = run + v.x;
        w.z = w.y + v.y;
        w.w = w.z + v.z;
        run = w.w + v.w;
        o4[i] = w;
    }
    if (t == 1023) off[N_NODES] = run;
}

// ---------------- scatter edges into CSR order + build degree-sorted node perm ----------------
// blocks [0,4096): edge scatter (atomic-free via rank); blocks [4096,4352): perm build.
__global__ __launch_bounds__(256) void k_scatter(
    const int* __restrict__ ei, const float* __restrict__ ea,
    const int* __restrict__ off, const int* __restrict__ rank,
    const int* __restrict__ deg, const int* __restrict__ boff, int* __restrict__ bcur,
    int* __restrict__ perm, int4* __restrict__ erec)
{
    if (blockIdx.x >= 4096) {
        int n = (blockIdx.x - 4096) * 256 + threadIdx.x;
        int d = deg[n]; d = d < 63 ? d : 63;
        int pos = boff[d] + atomicAdd(bcur + d, 1);
        perm[pos] = n;
        return;
    }
    int e = blockIdx.x * 256 + threadIdx.x;
    int src = ei[e];
    int dst = ei[N_EDGES + e];
    float a0 = ea[e * 3 + 0];
    float a1 = ea[e * 3 + 1];
    float a2 = ea[e * 3 + 2];
    int pos = off[dst] + rank[e];
    erec[pos] = make_int4(src, __float_as_int(a0), __float_as_int(a1), __float_as_int(a2));
}

// ---------------- fused node pipeline (MFMA): MLP(2x LN) -> xl8/xr/hres, + deg/rank fold ----------------
__global__ __launch_bounds__(256, 4) void k_fused(
    const float* __restrict__ in,
    const u16* __restrict__ wt0, const u16* __restrict__ wt1, const u16* __restrict__ wt,
    const float* __restrict__ b0, const float* __restrict__ g0, const float* __restrict__ be0,
    const float* __restrict__ b1, const float* __restrict__ g1, const float* __restrict__ be1,
    const float* __restrict__ bl, const float* __restrict__ br, const float* __restrict__ gbias,
    const int* __restrict__ ei, int* __restrict__ deg, int* __restrict__ rank,
    u8* __restrict__ xl8, u16* __restrict__ xr, u16* __restrict__ hres)
{
    if (blockIdx.x >= 1024) {
        int e = (blockIdx.x - 1024) * 256 + threadIdx.x;
        rank[e] = atomicAdd(deg + ei[N_EDGES + e], 1);   // rank = within-node slot
        return;
    }
    int wid = threadIdx.x >> 6, lane = threadIdx.x & 63;
    int l15 = lane & 15, quad = lane >> 4;
    int m0 = (blockIdx.x * 4 + wid) * 16;

    __shared__ u16 xbuf[4][16][136];   // per-wave x-strip (bf16)

    f32x4 acc[8];

    // ===== layer 0: [16 x 96] @ W0 -> [16 x 128], relu + LN =====
#pragma unroll
    for (int t = 0; t < 8; t++) acc[t] = {0.f, 0.f, 0.f, 0.f};
#pragma unroll
    for (int kk = 0; kk < 3; kk++) {
        const float* ap = in + (long)(m0 + l15) * IN_DIM + kk * 32 + quad * 8;
        float4 fa = *(const float4*)(ap);
        float4 fb = *(const float4*)(ap + 4);
        bf16x8 af;
        af[0] = (short)f2bf(fa.x); af[1] = (short)f2bf(fa.y);
        af[2] = (short)f2bf(fa.z); af[3] = (short)f2bf(fa.w);
        af[4] = (short)f2bf(fb.x); af[5] = (short)f2bf(fb.y);
        af[6] = (short)f2bf(fb.z); af[7] = (short)f2bf(fb.w);
#pragma unroll
        for (int t = 0; t < 8; t++) {
            bf16x8 bf = *(const bf16x8*)(wt0 + (t * 16 + l15) * IN_DIM + kk * 32 + quad * 8);
            acc[t] = __builtin_amdgcn_mfma_f32_16x16x32_bf16(af, bf, acc[t], 0, 0, 0);
        }
    }
    {
        float bv[8], gv[8], bev[8];
#pragma unroll
        for (int t = 0; t < 8; t++) {
            int col = t * 16 + l15;
            bv[t] = b0[col]; gv[t] = g0[col]; bev[t] = be0[col];
        }
#pragma unroll
        for (int g = 0; g < 4; g++) {
            float s_ = 0.f, q_ = 0.f;
#pragma unroll
            for (int t = 0; t < 8; t++) {
                float x = fmaxf(acc[t][g] + bv[t], 0.f);
                acc[t][g] = x;
                s_ += x;
                q_ = fmaf(x, x, q_);
            }
            s_ = red16(s_);
            q_ = red16(q_);
            float mu = s_ * (1.f / HID);
            float var = q_ * (1.f / HID) - mu * mu;
            float rs = rsqrtf(fmaxf(var, 0.f) + 1e-5f);
#pragma unroll
            for (int t = 0; t < 8; t++) {
                float y = (acc[t][g] - mu) * rs * gv[t] + bev[t];
                xbuf[wid][quad * 4 + g][t * 16 + l15] = f2bf(y);
            }
        }
    }

    // ===== layer 1: [16 x 128] @ W1 -> [16 x 128], relu + LN =====
#pragma unroll
    for (int t = 0; t < 8; t++) acc[t] = {0.f, 0.f, 0.f, 0.f};
#pragma unroll
    for (int kk = 0; kk < 4; kk++) {
        bf16x8 af = *(const bf16x8*)(&xbuf[wid][l15][kk * 32 + quad * 8]);
#pragma unroll
        for (int t = 0; t < 8; t++) {
            bf16x8 bf = *(const bf16x8*)(wt1 + (t * 16 + l15) * HID + kk * 32 + quad * 8);
            acc[t] = __builtin_amdgcn_mfma_f32_16x16x32_bf16(af, bf, acc[t], 0, 0, 0);
        }
    }
    {
        float bv[8], gv[8], bev[8];
#pragma unroll
        for (int t = 0; t < 8; t++) {
            int col = t * 16 + l15;
            bv[t] = b1[col]; gv[t] = g1[col]; bev[t] = be1[col];
        }
#pragma unroll
        for (int g = 0; g < 4; g++) {
            float s_ = 0.f, q_ = 0.f;
#pragma unroll
            for (int t = 0; t < 8; t++) {
                float x = fmaxf(acc[t][g] + bv[t], 0.f);
                acc[t][g] = x;
                s_ += x;
                q_ = fmaf(x, x, q_);
            }
            s_ = red16(s_);
            q_ = red16(q_);
            float mu = s_ * (1.f / HID);
            float var = q_ * (1.f / HID) - mu * mu;
            float rs = rsqrtf(fmaxf(var, 0.f) + 1e-5f);
#pragma unroll
            for (int t = 0; t < 8; t++) {
                float y = (acc[t][g] - mu) * rs * gv[t] + bev[t];
                xbuf[wid][quad * 4 + g][t * 16 + l15] = f2bf(y);
            }
        }
    }

    // ===== projections: x1 @ {Wl|Wr|Wres} + bias -> xl8(fp8 HW)/xr/hres =====
    for (int nT = 0; nT < 3; nT++) {
        f32x4 pacc[16];
#pragma unroll
        for (int t = 0; t < 16; t++) pacc[t] = {0.f, 0.f, 0.f, 0.f};
#pragma unroll
        for (int kk = 0; kk < 4; kk++) {
            bf16x8 af = *(const bf16x8*)(&xbuf[wid][l15][kk * 32 + quad * 8]);
#pragma unroll
            for (int t = 0; t < 16; t++) {
                bf16x8 bf = *(const bf16x8*)(wt + (long)(nT * 256 + t * 16 + l15) * HID + kk * 32 + quad * 8);
                pacc[t] = __builtin_amdgcn_mfma_f32_16x16x32_bf16(af, bf, pacc[t], 0, 0, 0);
            }
        }
        if (nT == 0) {
#pragma unroll
            for (int t = 0; t < 16; t++) {
                int col = t * 16 + l15;
                float bvv = bl[col];
#pragma unroll
                for (int g = 0; g < 4; g++) {
                    xl8[(long)(m0 + quad * 4 + g) * OUTD + col] = ftofp8_hw(pacc[t][g] + bvv);
                }
            }
        } else {
            const float* bias = (nT == 1) ? br : gbias;
            u16* dst = (nT == 1) ? xr : hres;
#pragma unroll
            for (int t = 0; t < 16; t++) {
                int col = t * 16 + l15;
                float bvv = bias[col];
#pragma unroll
                for (int g = 0; g < 4; g++) {
                    dst[(long)(m0 + quad * 4 + g) * OUTD + col] = f2bf(pacc[t][g] + bvv);
                }
            }
        }
    }
}

// ---------------- fused aggregation: plain-exp softmax, 2 edges/iter, pipelined, ----------------
// DPP wave-sum, fp8 HW decode, degree-sorted node order (perm) to kill the
// max-of-4-degrees block-lifetime tax.
__global__ __launch_bounds__(256, 6) void k_agg_fused(
    const int* __restrict__ perm,
    const int* __restrict__ off, const int4* __restrict__ erec,
    const u8* __restrict__ xl8, const u16* __restrict__ xr, const u16* __restrict__ hres,
    const float* __restrict__ We, const float* __restrict__ att,
    const float* __restrict__ g2, const float* __restrict__ be2,
    const float* __restrict__ wqT, const float* __restrict__ bq,
    float* __restrict__ out)
{
    int wid = threadIdx.x >> 6, lane = threadIdx.x & 63;
    int n = perm[blockIdx.x * 4 + wid];
    int j0 = lane * 4;
    __shared__ float lds[4][OUTD + 4];

    float4 w0 = *(const float4*)(We + j0);
    float4 w1 = *(const float4*)(We + OUTD + j0);
    float4 w2 = *(const float4*)(We + 2 * OUTD + j0);
    float4 av = *(const float4*)(att + j0);

    ushort4 xrv = *(const ushort4*)(xr + (long)n * OUTD + j0);
    float xr0 = bf2f(xrv.x), xr1 = bf2f(xrv.y), xr2 = bf2f(xrv.z), xr3 = bf2f(xrv.w);

    int beg = off[n], end = off[n + 1];

    float s = 0.f;
    float a0 = 0.f, a1 = 0.f, a2 = 0.f, a3 = 0.f;

    if (beg < end) {
        int4 r0 = erec[beg];
        int4 r1 = erec[(beg + 1 < end) ? beg + 1 : beg];
        u32 v0 = *(const u32*)(xl8 + (long)r0.x * OUTD + j0);
        u32 v1 = *(const u32*)(xl8 + (long)r1.x * OUTD + j0);

        for (int i = beg; i < end; i += 2) {
            int ip2 = (i + 2 < end) ? i + 2 : end - 1;
            int ip3 = (i + 3 < end) ? i + 3 : end - 1;
            int4 nr0 = erec[ip2];
            int4 nr1 = erec[ip3];
            u32 nv0 = *(const u32*)(xl8 + (long)nr0.x * OUTD + j0);
            u32 nv1 = *(const u32*)(xl8 + (long)nr1.x * OUTD + j0);

            f32x2 d00 = __builtin_amdgcn_cvt_pk_f32_fp8((int)v0, false);
            f32x2 d01 = __builtin_amdgcn_cvt_pk_f32_fp8((int)v0, true);
            f32x2 d10 = __builtin_amdgcn_cvt_pk_f32_fp8((int)v1, false);
            f32x2 d11 = __builtin_amdgcn_cvt_pk_f32_fp8((int)v1, true);
            float x00 = d00[0], x01 = d00[1], x02 = d01[0], x03 = d01[1];
            float x10 = d10[0], x11 = d10[1], x12 = d11[0], x13 = d11[1];

            float p0, p1;
            {
                float ea0 = __int_as_float(r0.y), ea1 = __int_as_float(r0.z), ea2 = __int_as_float(r0.w);
                float t0 = x00 + xr0 + ea0 * w0.x + ea1 * w1.x + ea2 * w2.x;
                float t1 = x01 + xr1 + ea0 * w0.y + ea1 * w1.y + ea2 * w2.y;
                float t2 = x02 + xr2 + ea0 * w0.z + ea1 * w1.z + ea2 * w2.z;
                float t3 = x03 + xr3 + ea0 * w0.w + ea1 * w1.w + ea2 * w2.w;
                p0 = fmaxf(t0, 0.2f * t0) * av.x;
                p0 = fmaf(fmaxf(t1, 0.2f * t1), av.y, p0);
                p0 = fmaf(fmaxf(t2, 0.2f * t2), av.z, p0);
                p0 = fmaf(fmaxf(t3, 0.2f * t3), av.w, p0);
            }
            {
                float ea0 = __int_as_float(r1.y), ea1 = __int_as_float(r1.z), ea2 = __int_as_float(r1.w);
                float t0 = x10 + xr0 + ea0 * w0.x + ea1 * w1.x + ea2 * w2.x;
                float t1 = x11 + xr1 + ea0 * w0.y + ea1 * w1.y + ea2 * w2.y;
                float t2 = x12 + xr2 + ea0 * w0.z + ea1 * w1.z + ea2 * w2.z;
                float t3 = x13 + xr3 + ea0 * w0.w + ea1 * w1.w + ea2 * w2.w;
                p1 = fmaxf(t0, 0.2f * t0) * av.x;
                p1 = fmaf(fmaxf(t1, 0.2f * t1), av.y, p1);
                p1 = fmaf(fmaxf(t2, 0.2f * t2), av.z, p1);
                p1 = fmaf(fmaxf(t3, 0.2f * t3), av.w, p1);
            }

            p0 = wave_sum_bcast(p0);
            p1 = wave_sum_bcast(p1);
            if (i + 1 >= end) p1 = -1.0e30f;   // exp -> 0

            float e0 = __expf(p0);
            float e1 = __expf(p1);
            s += e0 + e1;
            a0 = fmaf(e0, x00, fmaf(e1, x10, a0));
            a1 = fmaf(e0, x01, fmaf(e1, x11, a1));
            a2 = fmaf(e0, x02, fmaf(e1, x12, a2));
            a3 = fmaf(e0, x03, fmaf(e1, x13, a3));

            r0 = nr0; r1 = nr1; v0 = nv0; v1 = nv1;
        }
    }

    float inv = (end > beg) ? 1.f / s : 0.f;

    ushort4 hv = *(const ushort4*)(hres + (long)n * OUTD + j0);
    float h0 = fmaxf(fmaf(a0, inv, bf2f(hv.x)), 0.f);
    float h1 = fmaxf(fmaf(a1, inv, bf2f(hv.y)), 0.f);
    float h2 = fmaxf(fmaf(a2, inv, bf2f(hv.z)), 0.f);
    float h3 = fmaxf(fmaf(a3, inv, bf2f(hv.w)), 0.f);

    float sum = h0 + h1 + h2 + h3;
    float sq = h0 * h0 + h1 * h1 + h2 * h2 + h3 * h3;
    sum = wave_sum_bcast(sum);
    sq = wave_sum_bcast(sq);
    float mu = sum * (1.f / OUTD);
    float var = sq * (1.f / OUTD) - mu * mu;
    float rs = rsqrtf(fmaxf(var, 0.f) + 1e-5f);

    float4 gv = *(const float4*)(g2 + j0);
    float4 bv = *(const float4*)(be2 + j0);
    float4 y;
    y.x = (h0 - mu) * rs * gv.x + bv.x;
    y.y = (h1 - mu) * rs * gv.y + bv.y;
    y.z = (h2 - mu) * rs * gv.z + bv.z;
    y.w = (h3 - mu) * rs * gv.w + bv.w;
    *(float4*)(&lds[wid][j0]) = y;
    __syncthreads();

    if (lane < N_ACT) {
        const float* wq = wqT + lane * OUTD;
        float qv = bq[lane];
#pragma unroll 4
        for (int j = 0; j < OUTD; j += 4) {
            float4 lv = *(const float4*)(&lds[wid][j]);
            float4 wv = *(const float4*)(wq + j);
            qv = fmaf(lv.x, wv.x, qv);
            qv = fmaf(lv.y, wv.y, qv);
            qv = fmaf(lv.z, wv.z, qv);
            qv = fmaf(lv.w, wv.w, qv);
        }
        out[(long)n * N_ACT + lane] = qv;
    }
}

extern "C" void kernel_launch(void* const* d_in, const int* in_sizes, int n_in,
                              void* d_out, int out_size, void* d_ws, size_t ws_size,
                              hipStream_t stream) {
    (void)in_sizes; (void)n_in; (void)out_size; (void)ws_size;
    const float* inp  = (const float*)d_in[0];
    const int*   ei   = (const int*)d_in[1];
    const float* ea   = (const float*)d_in[2];
    const float* W0   = (const float*)d_in[3];
    const float* b0   = (const float*)d_in[4];
    const float* g0   = (const float*)d_in[5];
    const float* be0  = (const float*)d_in[6];
    const float* W1   = (const float*)d_in[7];
    const float* b1   = (const float*)d_in[8];
    const float* g1   = (const float*)d_in[9];
    const float* be1  = (const float*)d_in[10];
    const float* Wl   = (const float*)d_in[11];
    const float* bl   = (const float*)d_in[12];
    const float* Wr   = (const float*)d_in[13];
    const float* br   = (const float*)d_in[14];
    const float* We   = (const float*)d_in[15];
    const float* att  = (const float*)d_in[16];
    const float* Wres = (const float*)d_in[17];
    const float* gbias= (const float*)d_in[18];
    const float* g2   = (const float*)d_in[19];
    const float* be2  = (const float*)d_in[20];
    const float* Wq   = (const float*)d_in[21];
    const float* bq   = (const float*)d_in[22];
    float* out = (float*)d_out;

    char* ws = (char*)d_ws;
    size_t o = 0;
    auto alloc = [&](size_t bytes) -> void* {
        void* p = ws + o;
        o += (bytes + 255) & ~(size_t)255;
        return p;
    };
    u8*    xl8    = (u8*)   alloc((size_t)N_NODES * OUTD);        // 16 MiB (fp8 e4m3)
    u16*   xr     = (u16*)  alloc((size_t)N_NODES * OUTD * 2);    // 32 MiB
    u16*   hres   = (u16*)  alloc((size_t)N_NODES * OUTD * 2);    // 32 MiB
    int*   deg    = (int*)  alloc((size_t)N_NODES * 4);           // 256 KiB
    int*   off    = (int*)  alloc((size_t)(N_NODES + 1) * 4);
    int*   rank   = (int*)  alloc((size_t)N_EDGES * 4);           // 4 MiB
    int*   perm   = (int*)  alloc((size_t)N_NODES * 4);           // 256 KiB (degree-sorted)
    int*   boff   = (int*)  alloc((size_t)64 * 4);
    int*   bcur   = (int*)  alloc((size_t)64 * 4);
    int4*  erec   = (int4*) alloc((size_t)N_EDGES * 16);          // 16 MiB
    u16*   wt     = (u16*)  alloc((size_t)768 * HID * 2);         // 192 KiB
    u16*   wt0    = (u16*)  alloc((size_t)HID * IN_DIM * 2);      // 24 KiB
    u16*   wt1    = (u16*)  alloc((size_t)HID * HID * 2);         // 32 KiB
    float* wqT    = (float*)alloc((size_t)N_ACT * OUTD * 4);      // 20 KiB

    k_prep<<<772, 256, 0, stream>>>(deg, bcur, Wl, Wr, Wres, wt, W0, wt0, W1, wt1, Wq, wqT);
    k_fused<<<1024 + N_EDGES / 256, 256, 0, stream>>>(inp, wt0, wt1, wt,
        b0, g0, be0, b1, g1, be1, bl, br, gbias, ei, deg, rank, xl8, xr, hres);
    k_scan<<<1, 1024, 0, stream>>>(deg, off, boff);
    k_scatter<<<4096 + 256, 256, 0, stream>>>(ei, ea, off, rank, deg, boff, bcur, perm, erec);
    k_agg_fused<<<N_NODES / 4, 256, 0, stream>>>(perm, off, erec, xl8, xr, hres, We, att, g2, be2, wqT, bq, out);
}

// Round 20
// 619.285 us; speedup vs baseline: 1.2619x; 1.2619x over previous
//
#include <hip/hip_runtime.h>
#include <hip/hip_bf16.h>

#define N_NODES 65536
#define N_EDGES 1048576
#define IN_DIM 96
#define HID 128
#define OUTD 256
#define N_ACT 20

typedef unsigned short u16;
typedef unsigned char u8;
typedef unsigned int u32;
typedef __attribute__((ext_vector_type(8))) short bf16x8;
typedef __attribute__((ext_vector_type(4))) float f32x4;
typedef __attribute__((ext_vector_type(2))) float f32x2;

// intermediates bf16 (xr/hres) and fp8-e4m3 (xl, gather-path) ; all math fp32
__device__ __forceinline__ float bf2f(u16 v) { return __uint_as_float(((u32)v) << 16); }
__device__ __forceinline__ u16 f2bf(float f) {
    u32 x = __float_as_uint(f);
    return (u16)((x + 0x7fffu + ((x >> 16) & 1u)) >> 16);
}

// ---- fp8 via HW converters (V_CVT_PK_*) ----
__device__ __forceinline__ u8 ftofp8_hw(float f) {
    return (u8)((u32)__builtin_amdgcn_cvt_pk_fp8_f32(f, f, 0, false) & 0xffu);
}

// ---- DPP adds on the VALU pipe (ctrl must be a constant -> template) ----
template <int CTRL>
__device__ __forceinline__ float dppadd(float p) {
    return p + __uint_as_float((u32)__builtin_amdgcn_update_dpp(
        0, (int)__float_as_uint(p), CTRL, 0xF, 0xF, true));
}
// full-wave sum, result broadcast (readlane 63)
__device__ __forceinline__ float wave_sum_bcast(float p) {
    p = dppadd<0x111>(p);   // row_shr:1
    p = dppadd<0x112>(p);   // row_shr:2
    p = dppadd<0x114>(p);   // row_shr:4
    p = dppadd<0x118>(p);   // row_shr:8
    p = dppadd<0x142>(p);   // row_bcast15
    p = dppadd<0x143>(p);   // row_bcast31
    return __uint_as_float((u32)__builtin_amdgcn_readlane((int)__float_as_uint(p), 63));
}
// 16-lane (hw-row) sum, broadcast to all 16 lanes of the row.
__device__ __forceinline__ float red16(float p) {
    p = dppadd<0xB1>(p);
    p = dppadd<0x4E>(p);
    p = dppadd<0x141>(p);
    p = dppadd<0x140>(p);
    return p;
}

// ---------------- prep: zero deg + bf16 n-major weights + transpose Wq ----------------
__global__ __launch_bounds__(256) void k_prep(
    int* __restrict__ deg,
    const float* __restrict__ Wl, const float* __restrict__ Wr, const float* __restrict__ Wres,
    u16* __restrict__ wt,
    const float* __restrict__ W0, u16* __restrict__ wt0,
    const float* __restrict__ W1, u16* __restrict__ wt1,
    const float* __restrict__ Wq, float* __restrict__ wqT)
{
    int b = blockIdx.x, t = threadIdx.x;
    if (b < 256) {
        deg[b * 256 + t] = 0;
    } else if (b < 640) {
        int idx = (b - 256) * 256 + t;        // 0..98303  gat weights [768][128]
        int nn = idx >> 7, k = idx & 127;
        float v;
        if (nn < 256) v = Wl[k * OUTD + nn];
        else if (nn < 512) v = Wr[k * OUTD + (nn - 256)];
        else v = Wres[k * OUTD + (nn - 512)];
        wt[idx] = f2bf(v);
    } else if (b < 688) {
        int idx = (b - 640) * 256 + t;        // 0..12287  W0^T [128][96]
        int nn = idx / 96, k = idx - nn * 96;
        wt0[idx] = f2bf(W0[k * HID + nn]);
    } else if (b < 752) {
        int idx = (b - 688) * 256 + t;        // 0..16383  W1^T [128][128]
        int nn = idx >> 7, k = idx & 127;
        wt1[idx] = f2bf(W1[k * HID + nn]);
    } else {
        int idx = (b - 752) * 256 + t;        // 0..5119   Wq^T [20][256]
        int q = idx >> 8, d = idx & 255;
        wqT[q * OUTD + d] = Wq[d * N_ACT + q];
    }
}

// ---------------- exclusive scan of degrees -> CSR offsets (int4-vectorized) ----------------
__global__ __launch_bounds__(1024) void k_scan(const int* __restrict__ deg, int* __restrict__ off) {
    __shared__ int part[1024];
    int t = threadIdx.x;
    int base = t * 64;
    const int4* d4 = (const int4*)(deg + base);
    int s = 0;
#pragma unroll
    for (int i = 0; i < 16; i++) { int4 v = d4[i]; s += v.x + v.y + v.z + v.w; }
    part[t] = s;
    __syncthreads();
    for (int o = 1; o < 1024; o <<= 1) {
        int v = (t >= o) ? part[t - o] : 0;
        __syncthreads();
        part[t] += v;
        __syncthreads();
    }
    int run = (t == 0) ? 0 : part[t - 1];
    int4* o4 = (int4*)(off + base);
#pragma unroll
    for (int i = 0; i < 16; i++) {
        int4 v = d4[i];
        int4 w;
        w.x = run;
        w.y = run + v.x;
        w.z = w.y + v.y;
        w.w = w.z + v.z;
        run = w.w + v.w;
        o4[i] = w;
    }
    if (t == 1023) off[N_NODES] = run;
}

// ---------------- scatter edge records into CSR order (atomic-free: rank from deg pass) ----------------
__global__ __launch_bounds__(256) void k_scatter(
    const int* __restrict__ ei, const float* __restrict__ ea,
    const int* __restrict__ off, const int* __restrict__ rank,
    int4* __restrict__ erec)
{
    int e = blockIdx.x * 256 + threadIdx.x;
    int src = ei[e];
    int dst = ei[N_EDGES + e];
    float a0 = ea[e * 3 + 0];
    float a1 = ea[e * 3 + 1];
    float a2 = ea[e * 3 + 2];
    int pos = off[dst] + rank[e];
    erec[pos] = make_int4(src, __float_as_int(a0), __float_as_int(a1), __float_as_int(a2));
}

// ---------------- fused node pipeline (MFMA): MLP(2x LN) -> xl8/xr/hres, + deg/rank fold ----------------
// blocks [0,1024): 4 waves x 16 nodes; blocks [1024,5120): degree count + edge rank.
__global__ __launch_bounds__(256, 4) void k_fused(
    const float* __restrict__ in,
    const u16* __restrict__ wt0, const u16* __restrict__ wt1, const u16* __restrict__ wt,
    const float* __restrict__ b0, const float* __restrict__ g0, const float* __restrict__ be0,
    const float* __restrict__ b1, const float* __restrict__ g1, const float* __restrict__ be1,
    const float* __restrict__ bl, const float* __restrict__ br, const float* __restrict__ gbias,
    const int* __restrict__ ei, int* __restrict__ deg, int* __restrict__ rank,
    u8* __restrict__ xl8, u16* __restrict__ xr, u16* __restrict__ hres)
{
    if (blockIdx.x >= 1024) {
        int e = (blockIdx.x - 1024) * 256 + threadIdx.x;
        rank[e] = atomicAdd(deg + ei[N_EDGES + e], 1);   // rank = within-node slot
        return;
    }
    int wid = threadIdx.x >> 6, lane = threadIdx.x & 63;
    int l15 = lane & 15, quad = lane >> 4;
    int m0 = (blockIdx.x * 4 + wid) * 16;

    __shared__ u16 xbuf[4][16][136];   // per-wave x-strip (bf16)

    f32x4 acc[8];

    // ===== layer 0: [16 x 96] @ W0 -> [16 x 128], relu + LN =====
#pragma unroll
    for (int t = 0; t < 8; t++) acc[t] = {0.f, 0.f, 0.f, 0.f};
#pragma unroll
    for (int kk = 0; kk < 3; kk++) {
        const float* ap = in + (long)(m0 + l15) * IN_DIM + kk * 32 + quad * 8;
        float4 fa = *(const float4*)(ap);
        float4 fb = *(const float4*)(ap + 4);
        bf16x8 af;
        af[0] = (short)f2bf(fa.x); af[1] = (short)f2bf(fa.y);
        af[2] = (short)f2bf(fa.z); af[3] = (short)f2bf(fa.w);
        af[4] = (short)f2bf(fb.x); af[5] = (short)f2bf(fb.y);
        af[6] = (short)f2bf(fb.z); af[7] = (short)f2bf(fb.w);
#pragma unroll
        for (int t = 0; t < 8; t++) {
            bf16x8 bf = *(const bf16x8*)(wt0 + (t * 16 + l15) * IN_DIM + kk * 32 + quad * 8);
            acc[t] = __builtin_amdgcn_mfma_f32_16x16x32_bf16(af, bf, acc[t], 0, 0, 0);
        }
    }
    {
        float bv[8], gv[8], bev[8];
#pragma unroll
        for (int t = 0; t < 8; t++) {
            int col = t * 16 + l15;
            bv[t] = b0[col]; gv[t] = g0[col]; bev[t] = be0[col];
        }
#pragma unroll
        for (int g = 0; g < 4; g++) {
            float s_ = 0.f, q_ = 0.f;
#pragma unroll
            for (int t = 0; t < 8; t++) {
                float x = fmaxf(acc[t][g] + bv[t], 0.f);
                acc[t][g] = x;
                s_ += x;
                q_ = fmaf(x, x, q_);
            }
            s_ = red16(s_);
            q_ = red16(q_);
            float mu = s_ * (1.f / HID);
            float var = q_ * (1.f / HID) - mu * mu;
            float rs = rsqrtf(fmaxf(var, 0.f) + 1e-5f);
#pragma unroll
            for (int t = 0; t < 8; t++) {
                float y = (acc[t][g] - mu) * rs * gv[t] + bev[t];
                xbuf[wid][quad * 4 + g][t * 16 + l15] = f2bf(y);
            }
        }
    }

    // ===== layer 1: [16 x 128] @ W1 -> [16 x 128], relu + LN =====
#pragma unroll
    for (int t = 0; t < 8; t++) acc[t] = {0.f, 0.f, 0.f, 0.f};
#pragma unroll
    for (int kk = 0; kk < 4; kk++) {
        bf16x8 af = *(const bf16x8*)(&xbuf[wid][l15][kk * 32 + quad * 8]);
#pragma unroll
        for (int t = 0; t < 8; t++) {
            bf16x8 bf = *(const bf16x8*)(wt1 + (t * 16 + l15) * HID + kk * 32 + quad * 8);
            acc[t] = __builtin_amdgcn_mfma_f32_16x16x32_bf16(af, bf, acc[t], 0, 0, 0);
        }
    }
    {
        float bv[8], gv[8], bev[8];
#pragma unroll
        for (int t = 0; t < 8; t++) {
            int col = t * 16 + l15;
            bv[t] = b1[col]; gv[t] = g1[col]; bev[t] = be1[col];
        }
#pragma unroll
        for (int g = 0; g < 4; g++) {
            float s_ = 0.f, q_ = 0.f;
#pragma unroll
            for (int t = 0; t < 8; t++) {
                float x = fmaxf(acc[t][g] + bv[t], 0.f);
                acc[t][g] = x;
                s_ += x;
                q_ = fmaf(x, x, q_);
            }
            s_ = red16(s_);
            q_ = red16(q_);
            float mu = s_ * (1.f / HID);
            float var = q_ * (1.f / HID) - mu * mu;
            float rs = rsqrtf(fmaxf(var, 0.f) + 1e-5f);
#pragma unroll
            for (int t = 0; t < 8; t++) {
                float y = (acc[t][g] - mu) * rs * gv[t] + bev[t];
                xbuf[wid][quad * 4 + g][t * 16 + l15] = f2bf(y);
            }
        }
    }

    // ===== projections: x1 @ {Wl|Wr|Wres} + bias -> xl8(fp8 HW)/xr/hres =====
    for (int nT = 0; nT < 3; nT++) {
        f32x4 pacc[16];
#pragma unroll
        for (int t = 0; t < 16; t++) pacc[t] = {0.f, 0.f, 0.f, 0.f};
#pragma unroll
        for (int kk = 0; kk < 4; kk++) {
            bf16x8 af = *(const bf16x8*)(&xbuf[wid][l15][kk * 32 + quad * 8]);
#pragma unroll
            for (int t = 0; t < 16; t++) {
                bf16x8 bf = *(const bf16x8*)(wt + (long)(nT * 256 + t * 16 + l15) * HID + kk * 32 + quad * 8);
                pacc[t] = __builtin_amdgcn_mfma_f32_16x16x32_bf16(af, bf, pacc[t], 0, 0, 0);
            }
        }
        if (nT == 0) {
#pragma unroll
            for (int t = 0; t < 16; t++) {
                int col = t * 16 + l15;
                float bvv = bl[col];
#pragma unroll
                for (int g = 0; g < 4; g++) {
                    xl8[(long)(m0 + quad * 4 + g) * OUTD + col] = ftofp8_hw(pacc[t][g] + bvv);
                }
            }
        } else {
            const float* bias = (nT == 1) ? br : gbias;
            u16* dst = (nT == 1) ? xr : hres;
#pragma unroll
            for (int t = 0; t < 16; t++) {
                int col = t * 16 + l15;
                float bvv = bias[col];
#pragma unroll
                for (int g = 0; g < 4; g++) {
                    dst[(long)(m0 + quad * 4 + g) * OUTD + col] = f2bf(pacc[t][g] + bvv);
                }
            }
        }
    }
}

// ---------------- fused aggregation (best measured ~305 µs): plain-exp softmax, ----------------
// 2 edges/iter, pipelined, DPP wave-sum, fp8 HW pair-decode.
__global__ __launch_bounds__(256, 6) void k_agg_fused(
    const int* __restrict__ off, const int4* __restrict__ erec,
    const u8* __restrict__ xl8, const u16* __restrict__ xr, const u16* __restrict__ hres,
    const float* __restrict__ We, const float* __restrict__ att,
    const float* __restrict__ g2, const float* __restrict__ be2,
    const float* __restrict__ wqT, const float* __restrict__ bq,
    float* __restrict__ out)
{
    int wid = threadIdx.x >> 6, lane = threadIdx.x & 63;
    int n = blockIdx.x * 4 + wid;
    int j0 = lane * 4;
    __shared__ float lds[4][OUTD + 4];

    float4 w0 = *(const float4*)(We + j0);
    float4 w1 = *(const float4*)(We + OUTD + j0);
    float4 w2 = *(const float4*)(We + 2 * OUTD + j0);
    float4 av = *(const float4*)(att + j0);

    ushort4 xrv = *(const ushort4*)(xr + (long)n * OUTD + j0);
    float xr0 = bf2f(xrv.x), xr1 = bf2f(xrv.y), xr2 = bf2f(xrv.z), xr3 = bf2f(xrv.w);

    int beg = off[n], end = off[n + 1];

    float s = 0.f;
    float a0 = 0.f, a1 = 0.f, a2 = 0.f, a3 = 0.f;

    if (beg < end) {
        int4 r0 = erec[beg];
        int4 r1 = erec[(beg + 1 < end) ? beg + 1 : beg];
        u32 v0 = *(const u32*)(xl8 + (long)r0.x * OUTD + j0);
        u32 v1 = *(const u32*)(xl8 + (long)r1.x * OUTD + j0);

        for (int i = beg; i < end; i += 2) {
            int ip2 = (i + 2 < end) ? i + 2 : end - 1;
            int ip3 = (i + 3 < end) ? i + 3 : end - 1;
            int4 nr0 = erec[ip2];
            int4 nr1 = erec[ip3];
            u32 nv0 = *(const u32*)(xl8 + (long)nr0.x * OUTD + j0);
            u32 nv1 = *(const u32*)(xl8 + (long)nr1.x * OUTD + j0);

            // HW packed fp8 -> f32 decode (1 inst per pair)
            f32x2 d00 = __builtin_amdgcn_cvt_pk_f32_fp8((int)v0, false);
            f32x2 d01 = __builtin_amdgcn_cvt_pk_f32_fp8((int)v0, true);
            f32x2 d10 = __builtin_amdgcn_cvt_pk_f32_fp8((int)v1, false);
            f32x2 d11 = __builtin_amdgcn_cvt_pk_f32_fp8((int)v1, true);
            float x00 = d00[0], x01 = d00[1], x02 = d01[0], x03 = d01[1];
            float x10 = d10[0], x11 = d10[1], x12 = d11[0], x13 = d11[1];

            float p0, p1;
            {
                float ea0 = __int_as_float(r0.y), ea1 = __int_as_float(r0.z), ea2 = __int_as_float(r0.w);
                float t0 = x00 + xr0 + ea0 * w0.x + ea1 * w1.x + ea2 * w2.x;
                float t1 = x01 + xr1 + ea0 * w0.y + ea1 * w1.y + ea2 * w2.y;
                float t2 = x02 + xr2 + ea0 * w0.z + ea1 * w1.z + ea2 * w2.z;
                float t3 = x03 + xr3 + ea0 * w0.w + ea1 * w1.w + ea2 * w2.w;
                p0 = fmaxf(t0, 0.2f * t0) * av.x;
                p0 = fmaf(fmaxf(t1, 0.2f * t1), av.y, p0);
                p0 = fmaf(fmaxf(t2, 0.2f * t2), av.z, p0);
                p0 = fmaf(fmaxf(t3, 0.2f * t3), av.w, p0);
            }
            {
                float ea0 = __int_as_float(r1.y), ea1 = __int_as_float(r1.z), ea2 = __int_as_float(r1.w);
                float t0 = x10 + xr0 + ea0 * w0.x + ea1 * w1.x + ea2 * w2.x;
                float t1 = x11 + xr1 + ea0 * w0.y + ea1 * w1.y + ea2 * w2.y;
                float t2 = x12 + xr2 + ea0 * w0.z + ea1 * w1.z + ea2 * w2.z;
                float t3 = x13 + xr3 + ea0 * w0.w + ea1 * w1.w + ea2 * w2.w;
                p1 = fmaxf(t0, 0.2f * t0) * av.x;
                p1 = fmaf(fmaxf(t1, 0.2f * t1), av.y, p1);
                p1 = fmaf(fmaxf(t2, 0.2f * t2), av.z, p1);
                p1 = fmaf(fmaxf(t3, 0.2f * t3), av.w, p1);
            }

            p0 = wave_sum_bcast(p0);
            p1 = wave_sum_bcast(p1);
            if (i + 1 >= end) p1 = -1.0e30f;   // exp -> 0

            float e0 = __expf(p0);
            float e1 = __expf(p1);
            s += e0 + e1;
            a0 = fmaf(e0, x00, fmaf(e1, x10, a0));
            a1 = fmaf(e0, x01, fmaf(e1, x11, a1));
            a2 = fmaf(e0, x02, fmaf(e1, x12, a2));
            a3 = fmaf(e0, x03, fmaf(e1, x13, a3));

            r0 = nr0; r1 = nr1; v0 = nv0; v1 = nv1;
        }
    }

    float inv = (end > beg) ? 1.f / s : 0.f;

    ushort4 hv = *(const ushort4*)(hres + (long)n * OUTD + j0);
    float h0 = fmaxf(fmaf(a0, inv, bf2f(hv.x)), 0.f);
    float h1 = fmaxf(fmaf(a1, inv, bf2f(hv.y)), 0.f);
    float h2 = fmaxf(fmaf(a2, inv, bf2f(hv.z)), 0.f);
    float h3 = fmaxf(fmaf(a3, inv, bf2f(hv.w)), 0.f);

    float sum = h0 + h1 + h2 + h3;
    float sq = h0 * h0 + h1 * h1 + h2 * h2 + h3 * h3;
    sum = wave_sum_bcast(sum);
    sq = wave_sum_bcast(sq);
    float mu = sum * (1.f / OUTD);
    float var = sq * (1.f / OUTD) - mu * mu;
    float rs = rsqrtf(fmaxf(var, 0.f) + 1e-5f);

    float4 gv = *(const float4*)(g2 + j0);
    float4 bv = *(const float4*)(be2 + j0);
    float4 y;
    y.x = (h0 - mu) * rs * gv.x + bv.x;
    y.y = (h1 - mu) * rs * gv.y + bv.y;
    y.z = (h2 - mu) * rs * gv.z + bv.z;
    y.w = (h3 - mu) * rs * gv.w + bv.w;
    *(float4*)(&lds[wid][j0]) = y;
    __syncthreads();

    if (lane < N_ACT) {
        const float* wq = wqT + lane * OUTD;
        float qv = bq[lane];
#pragma unroll 4
        for (int j = 0; j < OUTD; j += 4) {
            float4 lv = *(const float4*)(&lds[wid][j]);
            float4 wv = *(const float4*)(wq + j);
            qv = fmaf(lv.x, wv.x, qv);
            qv = fmaf(lv.y, wv.y, qv);
            qv = fmaf(lv.z, wv.z, qv);
            qv = fmaf(lv.w, wv.w, qv);
        }
        out[(long)n * N_ACT + lane] = qv;
    }
}

extern "C" void kernel_launch(void* const* d_in, const int* in_sizes, int n_in,
                              void* d_out, int out_size, void* d_ws, size_t ws_size,
                              hipStream_t stream) {
    (void)in_sizes; (void)n_in; (void)out_size; (void)ws_size;
    const float* inp  = (const float*)d_in[0];
    const int*   ei   = (const int*)d_in[1];
    const float* ea   = (const float*)d_in[2];
    const float* W0   = (const float*)d_in[3];
    const float* b0   = (const float*)d_in[4];
    const float* g0   = (const float*)d_in[5];
    const float* be0  = (const float*)d_in[6];
    const float* W1   = (const float*)d_in[7];
    const float* b1   = (const float*)d_in[8];
    const float* g1   = (const float*)d_in[9];
    const float* be1  = (const float*)d_in[10];
    const float* Wl   = (const float*)d_in[11];
    const float* bl   = (const float*)d_in[12];
    const float* Wr   = (const float*)d_in[13];
    const float* br   = (const float*)d_in[14];
    const float* We   = (const float*)d_in[15];
    const float* att  = (const float*)d_in[16];
    const float* Wres = (const float*)d_in[17];
    const float* gbias= (const float*)d_in[18];
    const float* g2   = (const float*)d_in[19];
    const float* be2  = (const float*)d_in[20];
    const float* Wq   = (const float*)d_in[21];
    const float* bq   = (const float*)d_in[22];
    float* out = (float*)d_out;

    char* ws = (char*)d_ws;
    size_t o = 0;
    auto alloc = [&](size_t bytes) -> void* {
        void* p = ws + o;
        o += (bytes + 255) & ~(size_t)255;
        return p;
    };
    u8*    xl8    = (u8*)   alloc((size_t)N_NODES * OUTD);        // 16 MiB (fp8 e4m3)
    u16*   xr     = (u16*)  alloc((size_t)N_NODES * OUTD * 2);    // 32 MiB
    u16*   hres   = (u16*)  alloc((size_t)N_NODES * OUTD * 2);    // 32 MiB
    int*   deg    = (int*)  alloc((size_t)N_NODES * 4);           // 256 KiB
    int*   off    = (int*)  alloc((size_t)(N_NODES + 1) * 4);
    int*   rank   = (int*)  alloc((size_t)N_EDGES * 4);           // 4 MiB (edge slot from deg pass)
    int4*  erec   = (int4*) alloc((size_t)N_EDGES * 16);          // 16 MiB
    u16*   wt     = (u16*)  alloc((size_t)768 * HID * 2);         // 192 KiB  gat [768][128]
    u16*   wt0    = (u16*)  alloc((size_t)HID * IN_DIM * 2);      // 24 KiB   W0^T [128][96]
    u16*   wt1    = (u16*)  alloc((size_t)HID * HID * 2);         // 32 KiB   W1^T [128][128]
    float* wqT    = (float*)alloc((size_t)N_ACT * OUTD * 4);      // 20 KiB

    k_prep<<<772, 256, 0, stream>>>(deg, Wl, Wr, Wres, wt, W0, wt0, W1, wt1, Wq, wqT);
    k_fused<<<1024 + N_EDGES / 256, 256, 0, stream>>>(inp, wt0, wt1, wt,
        b0, g0, be0, b1, g1, be1, bl, br, gbias, ei, deg, rank, xl8, xr, hres);
    k_scan<<<1, 1024, 0, stream>>>(deg, off);
    k_scatter<<<N_EDGES / 256, 256, 0, stream>>>(ei, ea, off, rank, erec);
    k_agg_fused<<<N_NODES / 4, 256, 0, stream>>>(off, erec, xl8, xr, hres, We, att, g2, be2, wqT, bq, out);
}